// Round 12
// baseline (369.663 us; speedup 1.0000x reference)
//
#include <hip/hip_runtime.h>
#include <math.h>

#define NN 20000
#define EE 320000
#define DIN 256
#define DD 128
#define HHEADS 4
#define NCLS 7

typedef __attribute__((ext_vector_type(8))) __bf16 bf16x8;
typedef __attribute__((ext_vector_type(4))) float f32x4;
typedef __attribute__((ext_vector_type(2))) float f32x2;

__device__ __forceinline__ unsigned short f2bf(float f) {
  union { float f; unsigned int u; } c; c.f = f;
  unsigned int r = c.u + 0x7fffu + ((c.u >> 16) & 1u);  // RNE
  return (unsigned short)(r >> 16);
}
__device__ __forceinline__ __bf16 f2bf16(float f) {
  union { unsigned short u; __bf16 b; } cv; cv.u = f2bf(f); return cv.b;
}
// fp8 e4m3 (OCP on gfx950) encode/decode via HW converts
__device__ __forceinline__ unsigned char fp8enc(float v) {
  return (unsigned char)(__builtin_amdgcn_cvt_pk_fp8_f32(v, 0.f, 0, false) & 0xff);
}

// ---------------- utility ----------------
__global__ void zero_ints(int* __restrict__ p, int n) {
  int i = blockIdx.x * blockDim.x + threadIdx.x;
  if (i < n) p[i] = 0;
}

// ---------------- CSR build ----------------
__global__ void count_kernel(const int* __restrict__ ei, int* __restrict__ deg_src,
                             int* __restrict__ cnt_dst) {
  int e = blockIdx.x * blockDim.x + threadIdx.x;
  if (e >= EE) return;
  atomicAdd(&deg_src[ei[e]], 1);
  atomicAdd(&cnt_dst[ei[EE + e]], 1);
}

// 1024-thread scan; writes row_ptr AND fillp (scatter cursor)
__global__ __launch_bounds__(1024) void scan_kernel(const int* __restrict__ cnt,
                                                    int* __restrict__ row_ptr,
                                                    int* __restrict__ fillp) {
  __shared__ int wsum[16];
  __shared__ int carry_s;
  const int tid = threadIdx.x;
  const int wid = tid >> 6, lane = tid & 63;
  if (tid == 0) carry_s = 0;
  __syncthreads();
  for (int base = 0; base < NN; base += 1024) {
    int i = base + tid;
    int x = (i < NN) ? cnt[i] : 0;
    int v = x;
#pragma unroll
    for (int off = 1; off < 64; off <<= 1) {
      int t = __shfl_up(v, off);
      if (lane >= off) v += t;
    }
    if (lane == 63) wsum[wid] = v;
    __syncthreads();
    int woff = 0;
    for (int w = 0; w < wid; ++w) woff += wsum[w];
    int excl = carry_s + woff + v - x;
    if (i < NN) { row_ptr[i] = excl; fillp[i] = excl; }
    __syncthreads();
    if (tid == 1023) carry_s += woff + v;
    __syncthreads();
  }
  if (tid == 0) row_ptr[NN] = EE;
}

__global__ void scatter_kernel(const int* __restrict__ ei, int* __restrict__ fillp,
                               int* __restrict__ ssrc) {
  int e = blockIdx.x * blockDim.x + threadIdx.x;
  if (e >= EE) return;
  int s = ei[e], d = ei[EE + e];
  int pos = atomicAdd(&fillp[d], 1);
  ssrc[pos] = s;
}

// ---------------- degree-descending node order (counting sort) ----------------
__global__ void hist_kernel(const int* __restrict__ cnt, int* __restrict__ hist) {
  int i = blockIdx.x * blockDim.x + threadIdx.x;
  if (i < NN) atomicAdd(&hist[min(cnt[i], 255)], 1);
}
// binfill[d] = number of nodes with degree > d  (start offset for bin d, descending order)
__global__ void hscan_kernel(const int* __restrict__ hist, int* __restrict__ binfill) {
  const int tid = threadIdx.x;     // 256 threads
  const int rd = 255 - tid;
  const int lane = tid & 63, wid = tid >> 6;
  __shared__ int wsum[4];
  int x = hist[rd];
  int v = x;
#pragma unroll
  for (int off = 1; off < 64; off <<= 1) {
    int t = __shfl_up(v, off);
    if (lane >= off) v += t;
  }
  if (lane == 63) wsum[wid] = v;
  __syncthreads();
  int woff = 0;
  for (int w = 0; w < wid; ++w) woff += wsum[w];
  binfill[rd] = woff + v - x;
}
__global__ void fill_order_kernel(const int* __restrict__ cnt, int* __restrict__ binfill,
                                  int* __restrict__ order) {
  int i = blockIdx.x * blockDim.x + threadIdx.x;
  if (i >= NN) return;
  int d = min(cnt[i], 255);
  int pos = atomicAdd(&binfill[d], 1);
  order[pos] = i;
}

// ---------------- pack weights ----------------
// WT (bf16): W_inT[128][256] @0 | W2T[2][1664][128] @32768 | WcT[16][128] @458752
// W2T column order: [q 0-511][kv-blocked 512-1535][skip 1536-1663]
// kv region col rr (0-based): b=rr>>7, cc=rr&127, is_v=(cc>=64), dim=b*64+(cc&63)
//   -> output byte b*128 + ((cc&63)>>3)*16 + is_v*8 + (cc&7)  (contiguous 128B per block)
__global__ void pack_weights(const float* __restrict__ W_in, const float* __restrict__ Wq,
                             const float* __restrict__ Wk, const float* __restrict__ Wv,
                             const float* __restrict__ Wsk, const float* __restrict__ Wc,
                             __bf16* __restrict__ WT) {
  int idx = blockIdx.x * blockDim.x + threadIdx.x;
  if (idx >= 460800) return;
  float val;
  if (idx < 32768) {                       // W_inT: [m][k], m<128, k<256
    int m = idx >> 8, k = idx & 255;
    val = W_in[k * 128 + m];
  } else if (idx < 458752) {               // W2T: [l][r][kk]
    int t = idx - 32768;
    int l = t / 212992; int t2 = t - l * 212992;
    int r = t2 >> 7, kk = t2 & 127;
    if (r < 512) {
      val = Wq[l * 65536 + kk * 512 + r];
    } else if (r < 1536) {
      int rr = r - 512;
      int b = rr >> 7, cc = rr & 127;
      int dim = b * 64 + (cc & 63);
      val = (cc >= 64) ? Wv[l * 65536 + kk * 512 + dim]
                       : Wk[l * 65536 + kk * 512 + dim];
    } else {
      val = Wsk[l * 16384 + kk * 128 + (r - 1536)];
    }
  } else {                                 // WcT: [r][kk], r<16 (pad), kk<128
    int t = idx - 458752;
    int r = t >> 7, kk = t & 127;
    val = (r < NCLS) ? Wc[kk * NCLS + r] : 0.f;
  }
  WT[idx] = f2bf16(val);
}

// bcomb[2][1664] | bcpad[16]  (same kv column remap)
__global__ void pack_bias(const float* __restrict__ bq, const float* __restrict__ bk,
                          const float* __restrict__ bv, const float* __restrict__ bsk,
                          const float* __restrict__ bc, float* __restrict__ bcomb,
                          float* __restrict__ bcpad) {
  int idx = blockIdx.x * blockDim.x + threadIdx.x;
  if (idx < 3328) {
    int l = idx / 1664, r = idx % 1664;
    float v;
    if (r < 512) {
      v = bq[l * 512 + r];
    } else if (r < 1536) {
      int rr = r - 512;
      int b = rr >> 7, cc = rr & 127;
      int dim = b * 64 + (cc & 63);
      v = (cc >= 64) ? bv[l * 512 + dim] : bk[l * 512 + dim];
    } else {
      v = bsk[l * 128 + (r - 1536)];
    }
    bcomb[idx] = v;
  } else if (idx < 3344) {
    int r = idx - 3328;
    bcpad[r] = (r < NCLS) ? bc[r] : 0.f;
  }
}

// ---------------- input GEMM (K=256, fp32 A, cvt in staging): BM=64, BN=128 ----------------
__global__ __launch_bounds__(256) void mfma_gemm_in(
    const float* __restrict__ A, const __bf16* __restrict__ BT,
    const float* __restrict__ bias, float* __restrict__ o_f32,
    __bf16* __restrict__ o_bf0, const int* __restrict__ deg) {
  constexpr int K = 256;
  __shared__ __attribute__((aligned(16))) __bf16 As[64][136];
  __shared__ __attribute__((aligned(16))) __bf16 Bs[128][136];
  const int tid = threadIdx.x;
  const int brow = blockIdx.x * 64;
  const int wave = tid >> 6, lane = tid & 63;
  const int wm = wave & 1, wn = wave >> 1;
  const int lm = lane & 15, lk = (lane >> 4) * 8;
  const int srow16 = tid >> 4;
  const int sc8 = (tid & 15) * 8;
  f32x4 acc[2][4] = {};
  for (int k0 = 0; k0 < K; k0 += 128) {
    if (k0) __syncthreads();
#pragma unroll
    for (int t = 0; t < 4; ++t) {
      int row = t * 16 + srow16;
      int arow = brow + row;
      arow = (arow < NN) ? arow : (NN - 1);
      const float* ap = A + (size_t)arow * K + k0 + sc8;
      float4 a0 = *(const float4*)ap, a1 = *(const float4*)(ap + 4);
      uint4 w;
      w.x = (unsigned)f2bf(a0.x) | ((unsigned)f2bf(a0.y) << 16);
      w.y = (unsigned)f2bf(a0.z) | ((unsigned)f2bf(a0.w) << 16);
      w.z = (unsigned)f2bf(a1.x) | ((unsigned)f2bf(a1.y) << 16);
      w.w = (unsigned)f2bf(a1.z) | ((unsigned)f2bf(a1.w) << 16);
      *reinterpret_cast<uint4*>(&As[row][sc8]) = w;
    }
#pragma unroll
    for (int t = 0; t < 8; ++t) {
      int row = t * 16 + srow16;
      *reinterpret_cast<uint4*>(&Bs[row][sc8]) =
          *reinterpret_cast<const uint4*>(BT + (size_t)row * K + k0 + sc8);
    }
    __syncthreads();
#pragma unroll
    for (int ks = 0; ks < 4; ++ks) {
      bf16x8 af[2], bfr[4];
#pragma unroll
      for (int i = 0; i < 2; ++i)
        af[i] = *reinterpret_cast<const bf16x8*>(&As[wm * 32 + i * 16 + lm][ks * 32 + lk]);
#pragma unroll
      for (int j = 0; j < 4; ++j)
        bfr[j] = *reinterpret_cast<const bf16x8*>(&Bs[wn * 64 + j * 16 + lm][ks * 32 + lk]);
#pragma unroll
      for (int i = 0; i < 2; ++i)
#pragma unroll
        for (int j = 0; j < 4; ++j)
          acc[i][j] = __builtin_amdgcn_mfma_f32_16x16x32_bf16(af[i], bfr[j], acc[i][j], 0, 0, 0);
    }
  }
#pragma unroll
  for (int i = 0; i < 2; ++i) {
#pragma unroll
    for (int j = 0; j < 4; ++j) {
      const int col = wn * 64 + j * 16 + lm;
      const float bb = bias[col];
#pragma unroll
      for (int r = 0; r < 4; ++r) {
        const int row = brow + wm * 32 + i * 16 + (lane >> 4) * 4 + r;
        if (row >= NN) continue;
        float val = acc[i][j][r] + bb;
        float dg = (float)deg[row];
        float freq = dg * __expf(-0.07195578415606394f * (float)col);  // 10000^(-col/128)
        val += (col & 1) ? __cosf(freq) : __sinf(freq);
        o_f32[(size_t)row * DD + col] = val;
        o_bf0[(size_t)row * DD + col] = f2bf16(val);
      }
    }
  }
}

// ---------------- QKV GEMM: 8 waves, BM=128 x BN=128, B-in-LDS, A direct ----------------
// XCD-swizzled flat grid (2080 blocks): xcd gets a 20-rowblock stripe x all 13 col-blocks
// Epilogue: q and kv staged through LDS -> fully coalesced wide stores (no partial lines)
__global__ __launch_bounds__(512) void mfma_gemm_qkv(
    const __bf16* __restrict__ A, const __bf16* __restrict__ BT,
    const float* __restrict__ bias, const float* __restrict__ resid,
    __bf16* __restrict__ o_q, unsigned char* __restrict__ o_fp8,
    float* __restrict__ o_hs) {
  __shared__ __attribute__((aligned(16))) unsigned char smem[34816];
  auto Bs = reinterpret_cast<__bf16(*)[136]>(smem);

  const int bid = blockIdx.x;
  const int xcd = bid & 7;
  const int jj = bid >> 3;            // 0..259
  const int brow128 = xcd * 20 + (jj % 20);
  if (brow128 * 128 >= NN) return;
  const int brow = brow128 * 128;
  const int bcol = (jj / 20) * 128;   // 0..12 * 128

  const int tid = threadIdx.x;
  const int wave = tid >> 6, lane = tid & 63;
  const int wm = wave & 3, wn = wave >> 2;
  const int lm = lane & 15, lk = (lane >> 4) * 8, l4 = (lane >> 4) * 4;
  const int srow32 = tid >> 4;        // 0..31
  const int sc8 = (tid & 15) * 8;     // 0..120

  // B slice loads FIRST (pre-ds_write waitcnt drains only these 4)
  uint4 breg[4];
#pragma unroll
  for (int t = 0; t < 4; ++t)
    breg[t] = *reinterpret_cast<const uint4*>(BT + (size_t)(bcol + t * 32 + srow32) * 128 + sc8);

  // A fragments direct to registers (stay in flight across the barrier)
  bf16x8 af[2][4];
#pragma unroll
  for (int i = 0; i < 2; ++i) {
    int row = brow + wm * 32 + i * 16 + lm;
    row = (row < NN) ? row : (NN - 1);
    const __bf16* ap = A + (size_t)row * 128 + lk;
#pragma unroll
    for (int ks = 0; ks < 4; ++ks)
      af[i][ks] = *reinterpret_cast<const bf16x8*>(ap + ks * 32);
  }

#pragma unroll
  for (int t = 0; t < 4; ++t)
    *reinterpret_cast<uint4*>(&Bs[t * 32 + srow32][sc8]) = breg[t];
  __syncthreads();

  f32x4 acc[2][4] = {};
#pragma unroll
  for (int ks = 0; ks < 4; ++ks) {
    bf16x8 bfr[4];
#pragma unroll
    for (int j = 0; j < 4; ++j)
      bfr[j] = *reinterpret_cast<const bf16x8*>(&Bs[wn * 64 + j * 16 + lm][ks * 32 + lk]);
#pragma unroll
    for (int i = 0; i < 2; ++i)
#pragma unroll
      for (int j = 0; j < 4; ++j)
        acc[i][j] = __builtin_amdgcn_mfma_f32_16x16x32_bf16(af[i][ks], bfr[j], acc[i][j], 0, 0, 0);
  }

  __syncthreads();  // all Bs reads done; smem is reusable for epilogue staging

  if (bcol < 512) {
    // ---- q: stage bf16 tile [128][136], then 256B-per-row coalesced stores ----
    auto qt = reinterpret_cast<__bf16(*)[136]>(smem);
#pragma unroll
    for (int i = 0; i < 2; ++i)
#pragma unroll
      for (int j = 0; j < 4; ++j) {
        const int cc = wn * 64 + j * 16 + lm;
        const float bb = bias[bcol + cc];
#pragma unroll
        for (int r = 0; r < 4; ++r)
          qt[wm * 32 + i * 16 + l4 + r][cc] = f2bf16(acc[i][j][r] + bb);
      }
    __syncthreads();
#pragma unroll
    for (int p = 0; p < 4; ++p) {
      int slot = tid + p * 512;
      int row = slot >> 4, c = slot & 15;
      int grow = brow + row;
      if (grow < NN)
        *reinterpret_cast<uint4*>(o_q + (size_t)grow * 512 + bcol + c * 8) =
            *reinterpret_cast<const uint4*>(&qt[row][c * 8]);
    }
  } else if (bcol < 1536) {
    // ---- kv: stage fp8 byte tile [128][128] (XOR-swizzled), then 128B-per-row stores ----
    auto kt = reinterpret_cast<unsigned char(*)[128]>(smem);
    const int b = (bcol - 512) >> 7;
#pragma unroll
    for (int i = 0; i < 2; ++i)
#pragma unroll
      for (int j = 0; j < 4; ++j) {
        const float bb = bias[bcol + wn * 64 + j * 16 + lm];
        const int boff = (j * 2 + (lm >> 3)) * 16 + wn * 8 + (lm & 7);
#pragma unroll
        for (int r = 0; r < 4; ++r) {
          int lrow = wm * 32 + i * 16 + l4 + r;
          kt[lrow][boff ^ (((lrow >> 2) & 3) << 5)] = fp8enc(acc[i][j][r] + bb);
        }
      }
    __syncthreads();
#pragma unroll
    for (int p = 0; p < 2; ++p) {
      int slot = tid + p * 512;
      int row = slot >> 3, c = slot & 7;
      int grow = brow + row;
      if (grow < NN)
        *reinterpret_cast<uint4*>(o_fp8 + (size_t)grow * 1024 + b * 128 + c * 16) =
            *reinterpret_cast<const uint4*>(&kt[row][(c * 16) ^ (((row >> 2) & 3) << 5)]);
    }
  } else {
    // ---- hs: direct fp32 (full-line runs) + residual pre-sum ----
#pragma unroll
    for (int i = 0; i < 2; ++i)
#pragma unroll
      for (int j = 0; j < 4; ++j) {
        const int col = bcol + wn * 64 + j * 16 + lm;
        const float bb = bias[col];
#pragma unroll
        for (int r = 0; r < 4; ++r) {
          const int row = brow + wm * 32 + i * 16 + l4 + r;
          if (row >= NN) continue;
          o_hs[(size_t)row * DD + (col - 1536)] =
              acc[i][j][r] + bb + resid[(size_t)row * DD + (col - 1536)];
        }
      }
  }
}

// ---------------- classifier: out[N][7] = hb @ WcT + bc; 16-col B tile ----------------
__global__ __launch_bounds__(256) void mfma_gemm_cls(
    const __bf16* __restrict__ A, const __bf16* __restrict__ BT,
    const float* __restrict__ bias, float* __restrict__ out) {
  __shared__ __attribute__((aligned(16))) __bf16 Bs[16][136];
  const int tid = threadIdx.x;
  const int wave = tid >> 6, lane = tid & 63;
  const int lm = lane & 15, lk = (lane >> 4) * 8, l4 = (lane >> 4) * 4;
  const int brow = blockIdx.x * 128 + wave * 32;
  {  // stage 16 rows x 128 k
    int srow = tid >> 4, sc8 = (tid & 15) * 8;
    *reinterpret_cast<uint4*>(&Bs[srow][sc8]) =
        *reinterpret_cast<const uint4*>(BT + (size_t)srow * 128 + sc8);
  }
  __syncthreads();
  bf16x8 af[2][4];
#pragma unroll
  for (int i = 0; i < 2; ++i) {
    int row = brow + i * 16 + lm;
    row = (row < NN) ? row : (NN - 1);
    const __bf16* ap = A + (size_t)row * 128 + lk;
#pragma unroll
    for (int ks = 0; ks < 4; ++ks) af[i][ks] = *reinterpret_cast<const bf16x8*>(ap + ks * 32);
  }
  f32x4 acc[2] = {};
#pragma unroll
  for (int ks = 0; ks < 4; ++ks) {
    bf16x8 bfr = *reinterpret_cast<const bf16x8*>(&Bs[lm][ks * 32 + lk]);
#pragma unroll
    for (int i = 0; i < 2; ++i)
      acc[i] = __builtin_amdgcn_mfma_f32_16x16x32_bf16(af[i][ks], bfr, acc[i], 0, 0, 0);
  }
  if (lm < NCLS) {
    const float bb = bias[lm];
#pragma unroll
    for (int i = 0; i < 2; ++i) {
#pragma unroll
      for (int r = 0; r < 4; ++r) {
        int row = brow + i * 16 + l4 + r;
        if (row < NN) out[(size_t)row * NCLS + lm] = acc[i][r] + bb;
      }
    }
  }
}

// ---------------- attention helpers (packed f32) ----------------
__device__ __forceinline__ uint4 loadkv(const unsigned char* __restrict__ kv,
                                        const int* __restrict__ ssrc, int ee, int lane) {
  return *reinterpret_cast<const uint4*>(kv + (size_t)ssrc[ee] * 1024 + lane * 16);
}
__device__ __forceinline__ float qdot8(const f32x2 (&qv)[4], unsigned kx, unsigned ky) {
  f32x2 kd0 = __builtin_amdgcn_cvt_pk_f32_fp8((int)kx, false);
  f32x2 kd1 = __builtin_amdgcn_cvt_pk_f32_fp8((int)kx, true);
  f32x2 kd2 = __builtin_amdgcn_cvt_pk_f32_fp8((int)ky, false);
  f32x2 kd3 = __builtin_amdgcn_cvt_pk_f32_fp8((int)ky, true);
  f32x2 d2 = qv[0] * kd0;
  d2 = qv[1] * kd1 + d2;
  d2 = qv[2] * kd2 + d2;
  d2 = qv[3] * kd3 + d2;
  float d = d2[0] + d2[1];
  d += __shfl_xor(d, 1);
  d += __shfl_xor(d, 2);
  d += __shfl_xor(d, 4);
  d += __shfl_xor(d, 8);
  return d;
}
__device__ __forceinline__ void accum8(f32x2 (&a)[4], float& m, float& s, float sc,
                                       unsigned vz, unsigned vw) {
  if (sc > m) {  // rare after warm-up
    float c = __expf(m - sc);
    f32x2 c2 = {c, c};
    s *= c;
#pragma unroll
    for (int d = 0; d < 4; ++d) a[d] *= c2;
    m = sc;
  }
  float w = __expf(sc - m);
  s += w;
  f32x2 w2 = {w, w};
  f32x2 vd0 = __builtin_amdgcn_cvt_pk_f32_fp8((int)vz, false);
  f32x2 vd1 = __builtin_amdgcn_cvt_pk_f32_fp8((int)vz, true);
  f32x2 vd2 = __builtin_amdgcn_cvt_pk_f32_fp8((int)vw, false);
  f32x2 vd3 = __builtin_amdgcn_cvt_pk_f32_fp8((int)vw, true);
  a[0] = w2 * vd0 + a[0];
  a[1] = w2 * vd1 + a[1];
  a[2] = w2 * vd2 + a[2];
  a[3] = w2 * vd3 + a[3];
}

// ---------------- fused attention + head-mean + skip/resid + LN (+ReLU) ----------------
// wave = one dst node (4 heads), nodes processed in degree-descending order
__global__ __launch_bounds__(256) void attn_fused(
    const __bf16* __restrict__ qb, const unsigned char* __restrict__ kv,
    const float* __restrict__ hs, const int* __restrict__ order,
    const int* __restrict__ row_ptr, const int* __restrict__ ssrc,
    const float* __restrict__ ln_g, const float* __restrict__ ln_b,
    float* __restrict__ h_out, __bf16* __restrict__ hb_out, int relu_flag) {
  const int node = order[blockIdx.x * 4 + (threadIdx.x >> 6)];
  const int lane = threadIdx.x & 63;
  const int grp = lane >> 4, l16 = lane & 15;
  const int e0 = row_ptr[node], e1 = row_ptr[node + 1];
  const float scale = 0.088388347648318447f;  // 1/sqrt(128)

  f32x2 qv[4];
  {
    uint4 qw = *reinterpret_cast<const uint4*>(qb + (size_t)node * 512 + lane * 8);
    union { unsigned u; float f; } c;
    c.u = qw.x << 16; qv[0][0] = c.f; c.u = qw.x & 0xffff0000u; qv[0][1] = c.f;
    c.u = qw.y << 16; qv[1][0] = c.f; c.u = qw.y & 0xffff0000u; qv[1][1] = c.f;
    c.u = qw.z << 16; qv[2][0] = c.f; c.u = qw.z & 0xffff0000u; qv[2][1] = c.f;
    c.u = qw.w << 16; qv[3][0] = c.f; c.u = qw.w & 0xffff0000u; qv[3][1] = c.f;
  }
  float m = -INFINITY, s = 0.f;
  f32x2 a[4] = {};

  uint4 w0, w1, w2, w3;
  if (e0 + 0 < e1) w0 = loadkv(kv, ssrc, e0 + 0, lane);
  if (e0 + 1 < e1) w1 = loadkv(kv, ssrc, e0 + 1, lane);
  if (e0 + 2 < e1) w2 = loadkv(kv, ssrc, e0 + 2, lane);
  if (e0 + 3 < e1) w3 = loadkv(kv, ssrc, e0 + 3, lane);
  int e = e0;
  while (e < e1) {
    {
      float sc = qdot8(qv, w0.x, w0.y) * scale;
      unsigned vz = w0.z, vw = w0.w;
      if (e + 4 < e1) w0 = loadkv(kv, ssrc, e + 4, lane);
      accum8(a, m, s, sc, vz, vw);
    }
    if (e + 1 < e1) {
      float sc = qdot8(qv, w1.x, w1.y) * scale;
      unsigned vz = w1.z, vw = w1.w;
      if (e + 5 < e1) w1 = loadkv(kv, ssrc, e + 5, lane);
      accum8(a, m, s, sc, vz, vw);
    }
    if (e + 2 < e1) {
      float sc = qdot8(qv, w2.x, w2.y) * scale;
      unsigned vz = w2.z, vw = w2.w;
      if (e + 6 < e1) w2 = loadkv(kv, ssrc, e + 6, lane);
      accum8(a, m, s, sc, vz, vw);
    }
    if (e + 3 < e1) {
      float sc = qdot8(qv, w3.x, w3.y) * scale;
      unsigned vz = w3.z, vw = w3.w;
      if (e + 7 < e1) w3 = loadkv(kv, ssrc, e + 7, lane);
      accum8(a, m, s, sc, vz, vw);
    }
    e += 4;
  }

  // normalize per head, then head-mean via cross-group shuffles
  float inv = 0.25f / (s + 1e-16f);
  float am[8];
#pragma unroll
  for (int d = 0; d < 8; ++d) {
    float ad = a[d >> 1][d & 1] * inv;
    ad += __shfl_xor(ad, 16);
    ad += __shfl_xor(ad, 32);
    am[d] = ad;  // mean over heads, replicated in all groups
  }

  // skip+residual (pre-summed in hs) + LayerNorm
  const float4* hp = reinterpret_cast<const float4*>(hs + (size_t)node * DD + l16 * 8);
  float4 h0 = hp[0], h1 = hp[1];
  float val[8];
  val[0] = am[0] + h0.x; val[1] = am[1] + h0.y; val[2] = am[2] + h0.z; val[3] = am[3] + h0.w;
  val[4] = am[4] + h1.x; val[5] = am[5] + h1.y; val[6] = am[6] + h1.z; val[7] = am[7] + h1.w;
  float sum = 0.f, sq = 0.f;
#pragma unroll
  for (int d = 0; d < 8; ++d) { sum += val[d]; sq += val[d] * val[d]; }
  sum += __shfl_xor(sum, 1); sq += __shfl_xor(sq, 1);
  sum += __shfl_xor(sum, 2); sq += __shfl_xor(sq, 2);
  sum += __shfl_xor(sum, 4); sq += __shfl_xor(sq, 4);
  sum += __shfl_xor(sum, 8); sq += __shfl_xor(sq, 8);
  float mu = sum * (1.f / 128.f);
  float var = sq * (1.f / 128.f) - mu * mu;
  float rstd = rsqrtf(var + 1e-5f);

  const float4* gp = reinterpret_cast<const float4*>(ln_g + l16 * 8);
  const float4* bp = reinterpret_cast<const float4*>(ln_b + l16 * 8);
  float4 g0 = gp[0], g1 = gp[1];
  float4 b0 = bp[0], b1 = bp[1];
  float y[8];
  y[0] = (val[0] - mu) * rstd * g0.x + b0.x;
  y[1] = (val[1] - mu) * rstd * g0.y + b0.y;
  y[2] = (val[2] - mu) * rstd * g0.z + b0.z;
  y[3] = (val[3] - mu) * rstd * g0.w + b0.w;
  y[4] = (val[4] - mu) * rstd * g1.x + b1.x;
  y[5] = (val[5] - mu) * rstd * g1.y + b1.y;
  y[6] = (val[6] - mu) * rstd * g1.z + b1.z;
  y[7] = (val[7] - mu) * rstd * g1.w + b1.w;
  if (relu_flag) {
#pragma unroll
    for (int d = 0; d < 8; ++d) y[d] = fmaxf(y[d], 0.f);
  }
  if (grp == 0) {
    float4* op = reinterpret_cast<float4*>(h_out + (size_t)node * DD + l16 * 8);
    op[0] = make_float4(y[0], y[1], y[2], y[3]);
    op[1] = make_float4(y[4], y[5], y[6], y[7]);
  } else if (grp == 1) {
    uint4 w;
    w.x = (unsigned)f2bf(y[0]) | ((unsigned)f2bf(y[1]) << 16);
    w.y = (unsigned)f2bf(y[2]) | ((unsigned)f2bf(y[3]) << 16);
    w.z = (unsigned)f2bf(y[4]) | ((unsigned)f2bf(y[5]) << 16);
    w.w = (unsigned)f2bf(y[6]) | ((unsigned)f2bf(y[7]) << 16);
    *reinterpret_cast<uint4*>(hb_out + (size_t)node * DD + l16 * 8) = w;
  }
}

extern "C" void kernel_launch(void* const* d_in, const int* in_sizes, int n_in,
                              void* d_out, int out_size, void* d_ws, size_t ws_size,
                              hipStream_t stream) {
  const float* x    = (const float*)d_in[0];
  const int*   ei   = (const int*)d_in[1];
  const float* W_in = (const float*)d_in[2];
  const float* b_in = (const float*)d_in[3];
  const float* Wq   = (const float*)d_in[4];
  const float* bq   = (const float*)d_in[5];
  const float* Wk   = (const float*)d_in[6];
  const float* bk   = (const float*)d_in[7];
  const float* Wv   = (const float*)d_in[8];
  const float* bv   = (const float*)d_in[9];
  const float* Wsk  = (const float*)d_in[10];
  const float* bsk  = (const float*)d_in[11];
  const float* ln_g = (const float*)d_in[12];
  const float* ln_b = (const float*)d_in[13];
  const float* Wc   = (const float*)d_in[14];
  const float* bc   = (const float*)d_in[15];
  float* out = (float*)d_out;

  char* ws = (char*)d_ws;
  size_t off = 0;
  float*  hA    = (float*)(ws + off);  off += (size_t)NN * DD * 4;
  float*  hB    = (float*)(ws + off);  off += (size_t)NN * DD * 4;
  __bf16* qb    = (__bf16*)(ws + off); off += (size_t)NN * 512 * 2;
  unsigned char* kvb = (unsigned char*)(ws + off); off += (size_t)NN * 1024;
  float*  hsb   = (float*)(ws + off);  off += (size_t)NN * DD * 4;
  __bf16* hb0   = (__bf16*)(ws + off); off += (size_t)NN * DD * 2;
  __bf16* hb1   = (__bf16*)(ws + off); off += (size_t)NN * DD * 2;
  __bf16* WT    = (__bf16*)(ws + off); off += (size_t)460800 * 2;
  float*  bcomb = (float*)(ws + off);  off += (size_t)3328 * 4;
  float*  bcpad = (float*)(ws + off);  off += (size_t)16 * 4;
  int* deg      = (int*)(ws + off);    off += (size_t)NN * 4;
  int* cnt      = (int*)(ws + off);    off += (size_t)NN * 4;
  int* hist     = (int*)(ws + off);    off += (size_t)256 * 4;
  int* binfill  = (int*)(ws + off);    off += (size_t)256 * 4;
  int* fillp    = (int*)(ws + off);    off += (size_t)NN * 4;
  int* row_ptr  = (int*)(ws + off);    off += (size_t)(NN + 1) * 4;
  int* ssrc     = (int*)(ws + off);    off += (size_t)EE * 4;
  int* order    = (int*)(ws + off);    off += (size_t)NN * 4;

  __bf16* W_inT = WT;
  __bf16* W2T   = WT + 32768;
  __bf16* WcT   = WT + 458752;

  // zero deg+cnt+hist+binfill (contiguous)
  zero_ints<<<(2 * NN + 512 + 255) / 256, 256, 0, stream>>>(deg, 2 * NN + 512);
  count_kernel<<<(EE + 255) / 256, 256, 0, stream>>>(ei, deg, cnt);
  scan_kernel<<<1, 1024, 0, stream>>>(cnt, row_ptr, fillp);
  scatter_kernel<<<(EE + 255) / 256, 256, 0, stream>>>(ei, fillp, ssrc);

  // degree-descending order for attn load balance
  hist_kernel<<<(NN + 255) / 256, 256, 0, stream>>>(cnt, hist);
  hscan_kernel<<<1, 256, 0, stream>>>(hist, binfill);
  fill_order_kernel<<<(NN + 255) / 256, 256, 0, stream>>>(cnt, binfill, order);

  pack_weights<<<(460800 + 255) / 256, 256, 0, stream>>>(W_in, Wq, Wk, Wv, Wsk, Wc, WT);
  pack_bias<<<(3344 + 255) / 256, 256, 0, stream>>>(bq, bk, bv, bsk, bc, bcomb, bcpad);

  // h0 = x @ W_in + b_in + PE  -> hA (fp32) + hb0 (bf16)
  mfma_gemm_in<<<dim3((NN + 63) / 64, 1), 256, 0, stream>>>(x, W_inT, b_in, hA, hb0, deg);

  const float*  h_in_l[2]   = {hA, hB};
  float*        h_out_l[2]  = {hB, hA};
  const __bf16* hb_in_l[2]  = {hb0, hb1};
  __bf16*       hb_out_l[2] = {hb1, hb0};

  for (int l = 0; l < 2; ++l) {
    // XCD-swizzled flat grid: 8 xcds x 20 row-blocks x 13 col-blocks = 2080
    mfma_gemm_qkv<<<2080, 512, 0, stream>>>(hb_in_l[l], W2T + (size_t)l * 212992,
                                            bcomb + (size_t)l * 1664, h_in_l[l],
                                            qb, kvb, hsb);
    attn_fused<<<NN / 4, 256, 0, stream>>>(qb, kvb, hsb, order, row_ptr, ssrc,
                                           ln_g + (size_t)l * DD, ln_b + (size_t)l * DD,
                                           h_out_l[l], hb_out_l[l], (l == 0) ? 1 : 0);
  }

  // classifier: out = h @ Wc + bc  (A = hb0, final bf16 h)
  mfma_gemm_cls<<<dim3((NN + 127) / 128, 1), 256, 0, stream>>>(hb0, WcT, bcpad, out);
}

// Round 13
// 300.220 us; speedup vs baseline: 1.2313x; 1.2313x over previous
//
#include <hip/hip_runtime.h>
#include <math.h>

#define NN 20000
#define EE 320000
#define DIN 256
#define DD 128
#define HHEADS 4
#define NCLS 7

typedef __attribute__((ext_vector_type(8))) __bf16 bf16x8;
typedef __attribute__((ext_vector_type(4))) float f32x4;
typedef __attribute__((ext_vector_type(2))) float f32x2;

__device__ __forceinline__ unsigned short f2bf(float f) {
  union { float f; unsigned int u; } c; c.f = f;
  unsigned int r = c.u + 0x7fffu + ((c.u >> 16) & 1u);  // RNE
  return (unsigned short)(r >> 16);
}
__device__ __forceinline__ __bf16 f2bf16(float f) {
  union { unsigned short u; __bf16 b; } cv; cv.u = f2bf(f); return cv.b;
}
// fp8 e4m3 (OCP on gfx950) encode/decode via HW converts
__device__ __forceinline__ unsigned char fp8enc(float v) {
  return (unsigned char)(__builtin_amdgcn_cvt_pk_fp8_f32(v, 0.f, 0, false) & 0xff);
}

// ---------------- utility ----------------
__global__ void zero_ints(int* __restrict__ p, int n) {
  int i = blockIdx.x * blockDim.x + threadIdx.x;
  if (i < n) p[i] = 0;
}

// ---------------- CSR build ----------------
__global__ void count_kernel(const int* __restrict__ ei, int* __restrict__ deg_src,
                             int* __restrict__ cnt_dst) {
  int e = blockIdx.x * blockDim.x + threadIdx.x;
  if (e >= EE) return;
  atomicAdd(&deg_src[ei[e]], 1);
  atomicAdd(&cnt_dst[ei[EE + e]], 1);
}

// 1024-thread scan; writes row_ptr AND fillp (scatter cursor)
__global__ __launch_bounds__(1024) void scan_kernel(const int* __restrict__ cnt,
                                                    int* __restrict__ row_ptr,
                                                    int* __restrict__ fillp) {
  __shared__ int wsum[16];
  __shared__ int carry_s;
  const int tid = threadIdx.x;
  const int wid = tid >> 6, lane = tid & 63;
  if (tid == 0) carry_s = 0;
  __syncthreads();
  for (int base = 0; base < NN; base += 1024) {
    int i = base + tid;
    int x = (i < NN) ? cnt[i] : 0;
    int v = x;
#pragma unroll
    for (int off = 1; off < 64; off <<= 1) {
      int t = __shfl_up(v, off);
      if (lane >= off) v += t;
    }
    if (lane == 63) wsum[wid] = v;
    __syncthreads();
    int woff = 0;
    for (int w = 0; w < wid; ++w) woff += wsum[w];
    int excl = carry_s + woff + v - x;
    if (i < NN) { row_ptr[i] = excl; fillp[i] = excl; }
    __syncthreads();
    if (tid == 1023) carry_s += woff + v;
    __syncthreads();
  }
  if (tid == 0) row_ptr[NN] = EE;
}

__global__ void scatter_kernel(const int* __restrict__ ei, int* __restrict__ fillp,
                               int* __restrict__ ssrc) {
  int e = blockIdx.x * blockDim.x + threadIdx.x;
  if (e >= EE) return;
  int s = ei[e], d = ei[EE + e];
  int pos = atomicAdd(&fillp[d], 1);
  ssrc[pos] = s;
}

// ---------------- pack weights ----------------
// WT (bf16): W_inT[128][256] @0 | W2T[2][1664][128] @32768 ; total 458752
// W2T column order: [q 0-511][kv-blocked 512-1535][skip 1536-1663]
// kv region col rr (0-based): b=rr>>7, cc=rr&127, is_v=(cc>=64), dim=b*64+(cc&63)
//   -> output byte b*128 + ((cc&63)>>3)*16 + is_v*8 + (cc&7)  (contiguous 128B per block)
__global__ void pack_weights(const float* __restrict__ W_in, const float* __restrict__ Wq,
                             const float* __restrict__ Wk, const float* __restrict__ Wv,
                             const float* __restrict__ Wsk, __bf16* __restrict__ WT) {
  int idx = blockIdx.x * blockDim.x + threadIdx.x;
  if (idx >= 458752) return;
  float val;
  if (idx < 32768) {                       // W_inT: [m][k], m<128, k<256
    int m = idx >> 8, k = idx & 255;
    val = W_in[k * 128 + m];
  } else {                                 // W2T: [l][r][kk]
    int t = idx - 32768;
    int l = t / 212992; int t2 = t - l * 212992;
    int r = t2 >> 7, kk = t2 & 127;
    if (r < 512) {
      val = Wq[l * 65536 + kk * 512 + r];
    } else if (r < 1536) {
      int rr = r - 512;
      int b = rr >> 7, cc = rr & 127;
      int dim = b * 64 + (cc & 63);
      val = (cc >= 64) ? Wv[l * 65536 + kk * 512 + dim]
                       : Wk[l * 65536 + kk * 512 + dim];
    } else {
      val = Wsk[l * 16384 + kk * 128 + (r - 1536)];
    }
  }
  WT[idx] = f2bf16(val);
}

// bcomb[2][1664]  (same kv column remap)
__global__ void pack_bias(const float* __restrict__ bq, const float* __restrict__ bk,
                          const float* __restrict__ bv, const float* __restrict__ bsk,
                          float* __restrict__ bcomb) {
  int idx = blockIdx.x * blockDim.x + threadIdx.x;
  if (idx >= 3328) return;
  int l = idx / 1664, r = idx % 1664;
  float v;
  if (r < 512) {
    v = bq[l * 512 + r];
  } else if (r < 1536) {
    int rr = r - 512;
    int b = rr >> 7, cc = rr & 127;
    int dim = b * 64 + (cc & 63);
    v = (cc >= 64) ? bv[l * 512 + dim] : bk[l * 512 + dim];
  } else {
    v = bsk[l * 128 + (r - 1536)];
  }
  bcomb[idx] = v;
}

// ---------------- input GEMM (K=256, fp32 A, cvt in staging): BM=64, BN=128 ----------------
__global__ __launch_bounds__(256) void mfma_gemm_in(
    const float* __restrict__ A, const __bf16* __restrict__ BT,
    const float* __restrict__ bias, float* __restrict__ o_f32,
    __bf16* __restrict__ o_bf0, const int* __restrict__ deg) {
  constexpr int K = 256;
  __shared__ __attribute__((aligned(16))) __bf16 As[64][136];
  __shared__ __attribute__((aligned(16))) __bf16 Bs[128][136];
  const int tid = threadIdx.x;
  const int brow = blockIdx.x * 64;
  const int wave = tid >> 6, lane = tid & 63;
  const int wm = wave & 1, wn = wave >> 1;
  const int lm = lane & 15, lk = (lane >> 4) * 8;
  const int srow16 = tid >> 4;
  const int sc8 = (tid & 15) * 8;
  f32x4 acc[2][4] = {};
  for (int k0 = 0; k0 < K; k0 += 128) {
    if (k0) __syncthreads();
#pragma unroll
    for (int t = 0; t < 4; ++t) {
      int row = t * 16 + srow16;
      int arow = brow + row;
      arow = (arow < NN) ? arow : (NN - 1);
      const float* ap = A + (size_t)arow * K + k0 + sc8;
      float4 a0 = *(const float4*)ap, a1 = *(const float4*)(ap + 4);
      uint4 w;
      w.x = (unsigned)f2bf(a0.x) | ((unsigned)f2bf(a0.y) << 16);
      w.y = (unsigned)f2bf(a0.z) | ((unsigned)f2bf(a0.w) << 16);
      w.z = (unsigned)f2bf(a1.x) | ((unsigned)f2bf(a1.y) << 16);
      w.w = (unsigned)f2bf(a1.z) | ((unsigned)f2bf(a1.w) << 16);
      *reinterpret_cast<uint4*>(&As[row][sc8]) = w;
    }
#pragma unroll
    for (int t = 0; t < 8; ++t) {
      int row = t * 16 + srow16;
      *reinterpret_cast<uint4*>(&Bs[row][sc8]) =
          *reinterpret_cast<const uint4*>(BT + (size_t)row * K + k0 + sc8);
    }
    __syncthreads();
#pragma unroll
    for (int ks = 0; ks < 4; ++ks) {
      bf16x8 af[2], bfr[4];
#pragma unroll
      for (int i = 0; i < 2; ++i)
        af[i] = *reinterpret_cast<const bf16x8*>(&As[wm * 32 + i * 16 + lm][ks * 32 + lk]);
#pragma unroll
      for (int j = 0; j < 4; ++j)
        bfr[j] = *reinterpret_cast<const bf16x8*>(&Bs[wn * 64 + j * 16 + lm][ks * 32 + lk]);
#pragma unroll
      for (int i = 0; i < 2; ++i)
#pragma unroll
        for (int j = 0; j < 4; ++j)
          acc[i][j] = __builtin_amdgcn_mfma_f32_16x16x32_bf16(af[i], bfr[j], acc[i][j], 0, 0, 0);
    }
  }
#pragma unroll
  for (int i = 0; i < 2; ++i) {
#pragma unroll
    for (int j = 0; j < 4; ++j) {
      const int col = wn * 64 + j * 16 + lm;
      const float bb = bias[col];
#pragma unroll
      for (int r = 0; r < 4; ++r) {
        const int row = brow + wm * 32 + i * 16 + (lane >> 4) * 4 + r;
        if (row >= NN) continue;
        float val = acc[i][j][r] + bb;
        float dg = (float)deg[row];
        float freq = dg * __expf(-0.07195578415606394f * (float)col);  // 10000^(-col/128)
        val += (col & 1) ? __cosf(freq) : __sinf(freq);
        o_f32[(size_t)row * DD + col] = val;
        o_bf0[(size_t)row * DD + col] = f2bf16(val);
      }
    }
  }
}

// ---------------- QKV GEMM: 8 waves, BM=128 x BN=128, B-in-LDS, A direct ----------------
// XCD-swizzled flat grid (2080 blocks): xcd gets a 20-rowblock stripe x all 13 col-blocks
// Epilogue: q and kv staged through LDS -> fully coalesced wide stores (no partial lines)
__global__ __launch_bounds__(512) void mfma_gemm_qkv(
    const __bf16* __restrict__ A, const __bf16* __restrict__ BT,
    const float* __restrict__ bias, const float* __restrict__ resid,
    __bf16* __restrict__ o_q, unsigned char* __restrict__ o_fp8,
    float* __restrict__ o_hs) {
  __shared__ __attribute__((aligned(16))) unsigned char smem[34816];
  auto Bs = reinterpret_cast<__bf16(*)[136]>(smem);

  const int bid = blockIdx.x;
  const int xcd = bid & 7;
  const int jj = bid >> 3;            // 0..259
  const int brow128 = xcd * 20 + (jj % 20);
  if (brow128 * 128 >= NN) return;
  const int brow = brow128 * 128;
  const int bcol = (jj / 20) * 128;   // 0..12 * 128

  const int tid = threadIdx.x;
  const int wave = tid >> 6, lane = tid & 63;
  const int wm = wave & 3, wn = wave >> 2;
  const int lm = lane & 15, lk = (lane >> 4) * 8, l4 = (lane >> 4) * 4;
  const int srow32 = tid >> 4;        // 0..31
  const int sc8 = (tid & 15) * 8;     // 0..120

  // B slice loads FIRST (pre-ds_write waitcnt drains only these 4)
  uint4 breg[4];
#pragma unroll
  for (int t = 0; t < 4; ++t)
    breg[t] = *reinterpret_cast<const uint4*>(BT + (size_t)(bcol + t * 32 + srow32) * 128 + sc8);

  // A fragments direct to registers (stay in flight across the barrier)
  bf16x8 af[2][4];
#pragma unroll
  for (int i = 0; i < 2; ++i) {
    int row = brow + wm * 32 + i * 16 + lm;
    row = (row < NN) ? row : (NN - 1);
    const __bf16* ap = A + (size_t)row * 128 + lk;
#pragma unroll
    for (int ks = 0; ks < 4; ++ks)
      af[i][ks] = *reinterpret_cast<const bf16x8*>(ap + ks * 32);
  }

#pragma unroll
  for (int t = 0; t < 4; ++t)
    *reinterpret_cast<uint4*>(&Bs[t * 32 + srow32][sc8]) = breg[t];
  __syncthreads();

  f32x4 acc[2][4] = {};
#pragma unroll
  for (int ks = 0; ks < 4; ++ks) {
    bf16x8 bfr[4];
#pragma unroll
    for (int j = 0; j < 4; ++j)
      bfr[j] = *reinterpret_cast<const bf16x8*>(&Bs[wn * 64 + j * 16 + lm][ks * 32 + lk]);
#pragma unroll
    for (int i = 0; i < 2; ++i)
#pragma unroll
      for (int j = 0; j < 4; ++j)
        acc[i][j] = __builtin_amdgcn_mfma_f32_16x16x32_bf16(af[i][ks], bfr[j], acc[i][j], 0, 0, 0);
  }

  __syncthreads();  // all Bs reads done; smem is reusable for epilogue staging

  if (bcol < 512) {
    // ---- q: stage bf16 tile [128][136], then 256B-per-row coalesced stores ----
    auto qt = reinterpret_cast<__bf16(*)[136]>(smem);
#pragma unroll
    for (int i = 0; i < 2; ++i)
#pragma unroll
      for (int j = 0; j < 4; ++j) {
        const int cc = wn * 64 + j * 16 + lm;
        const float bb = bias[bcol + cc];
#pragma unroll
        for (int r = 0; r < 4; ++r)
          qt[wm * 32 + i * 16 + l4 + r][cc] = f2bf16(acc[i][j][r] + bb);
      }
    __syncthreads();
#pragma unroll
    for (int p = 0; p < 4; ++p) {
      int slot = tid + p * 512;
      int row = slot >> 4, c = slot & 15;
      int grow = brow + row;
      if (grow < NN)
        *reinterpret_cast<uint4*>(o_q + (size_t)grow * 512 + bcol + c * 8) =
            *reinterpret_cast<const uint4*>(&qt[row][c * 8]);
    }
  } else if (bcol < 1536) {
    // ---- kv: stage fp8 byte tile [128][128] (XOR-swizzled), then 128B-per-row stores ----
    auto kt = reinterpret_cast<unsigned char(*)[128]>(smem);
    const int b = (bcol - 512) >> 7;
#pragma unroll
    for (int i = 0; i < 2; ++i)
#pragma unroll
      for (int j = 0; j < 4; ++j) {
        const float bb = bias[bcol + wn * 64 + j * 16 + lm];
        const int boff = (j * 2 + (lm >> 3)) * 16 + wn * 8 + (lm & 7);
#pragma unroll
        for (int r = 0; r < 4; ++r) {
          int lrow = wm * 32 + i * 16 + l4 + r;
          kt[lrow][boff ^ (((lrow >> 2) & 3) << 5)] = fp8enc(acc[i][j][r] + bb);
        }
      }
    __syncthreads();
#pragma unroll
    for (int p = 0; p < 2; ++p) {
      int slot = tid + p * 512;
      int row = slot >> 3, c = slot & 7;
      int grow = brow + row;
      if (grow < NN)
        *reinterpret_cast<uint4*>(o_fp8 + (size_t)grow * 1024 + b * 128 + c * 16) =
            *reinterpret_cast<const uint4*>(&kt[row][(c * 16) ^ (((row >> 2) & 3) << 5)]);
    }
  } else {
    // ---- hs: direct fp32 (full-line runs) + residual pre-sum ----
#pragma unroll
    for (int i = 0; i < 2; ++i)
#pragma unroll
      for (int j = 0; j < 4; ++j) {
        const int col = bcol + wn * 64 + j * 16 + lm;
        const float bb = bias[col];
#pragma unroll
        for (int r = 0; r < 4; ++r) {
          const int row = brow + wm * 32 + i * 16 + l4 + r;
          if (row >= NN) continue;
          o_hs[(size_t)row * DD + (col - 1536)] =
              acc[i][j][r] + bb + resid[(size_t)row * DD + (col - 1536)];
        }
      }
  }
}

// ---------------- attention helpers (packed f32) ----------------
__device__ __forceinline__ uint4 loadkv(const unsigned char* __restrict__ kv,
                                        const int* __restrict__ ssrc, int ee, int lane) {
  return *reinterpret_cast<const uint4*>(kv + (size_t)ssrc[ee] * 1024 + lane * 16);
}
__device__ __forceinline__ float qdot8(const f32x2 (&qv)[4], unsigned kx, unsigned ky) {
  f32x2 kd0 = __builtin_amdgcn_cvt_pk_f32_fp8((int)kx, false);
  f32x2 kd1 = __builtin_amdgcn_cvt_pk_f32_fp8((int)kx, true);
  f32x2 kd2 = __builtin_amdgcn_cvt_pk_f32_fp8((int)ky, false);
  f32x2 kd3 = __builtin_amdgcn_cvt_pk_f32_fp8((int)ky, true);
  f32x2 d2 = qv[0] * kd0;
  d2 = qv[1] * kd1 + d2;
  d2 = qv[2] * kd2 + d2;
  d2 = qv[3] * kd3 + d2;
  float d = d2[0] + d2[1];
  d += __shfl_xor(d, 1);
  d += __shfl_xor(d, 2);
  d += __shfl_xor(d, 4);
  d += __shfl_xor(d, 8);
  return d;
}
__device__ __forceinline__ void accum8(f32x2 (&a)[4], float& m, float& s, float sc,
                                       unsigned vz, unsigned vw) {
  if (sc > m) {  // rare after warm-up
    float c = __expf(m - sc);
    f32x2 c2 = {c, c};
    s *= c;
#pragma unroll
    for (int d = 0; d < 4; ++d) a[d] *= c2;
    m = sc;
  }
  float w = __expf(sc - m);
  s += w;
  f32x2 w2 = {w, w};
  f32x2 vd0 = __builtin_amdgcn_cvt_pk_f32_fp8((int)vz, false);
  f32x2 vd1 = __builtin_amdgcn_cvt_pk_f32_fp8((int)vz, true);
  f32x2 vd2 = __builtin_amdgcn_cvt_pk_f32_fp8((int)vw, false);
  f32x2 vd3 = __builtin_amdgcn_cvt_pk_f32_fp8((int)vw, true);
  a[0] = w2 * vd0 + a[0];
  a[1] = w2 * vd1 + a[1];
  a[2] = w2 * vd2 + a[2];
  a[3] = w2 * vd3 + a[3];
}

// ---------------- fused attention + head-mean + skip/resid + LN (+ReLU) [+classifier] ----------------
// wave = one dst node (4 heads); 16-lane group = head; lane owns 8 dims.
// Layer 1 (out_cls != nullptr): classifier fused, h/hb stores skipped.
__global__ __launch_bounds__(256) void attn_fused(
    const __bf16* __restrict__ qb, const unsigned char* __restrict__ kv,
    const float* __restrict__ hs,
    const int* __restrict__ row_ptr, const int* __restrict__ ssrc,
    const float* __restrict__ ln_g, const float* __restrict__ ln_b,
    float* __restrict__ h_out, __bf16* __restrict__ hb_out, int relu_flag,
    const float* __restrict__ Wc, const float* __restrict__ bc,
    float* __restrict__ out_cls) {
  const int node = blockIdx.x * 4 + (threadIdx.x >> 6);
  const int lane = threadIdx.x & 63;
  const int grp = lane >> 4, l16 = lane & 15;
  const int e0 = row_ptr[node], e1 = row_ptr[node + 1];
  const float scale = 0.088388347648318447f;  // 1/sqrt(128)

  f32x2 qv[4];
  {
    uint4 qw = *reinterpret_cast<const uint4*>(qb + (size_t)node * 512 + lane * 8);
    union { unsigned u; float f; } c;
    c.u = qw.x << 16; qv[0][0] = c.f; c.u = qw.x & 0xffff0000u; qv[0][1] = c.f;
    c.u = qw.y << 16; qv[1][0] = c.f; c.u = qw.y & 0xffff0000u; qv[1][1] = c.f;
    c.u = qw.z << 16; qv[2][0] = c.f; c.u = qw.z & 0xffff0000u; qv[2][1] = c.f;
    c.u = qw.w << 16; qv[3][0] = c.f; c.u = qw.w & 0xffff0000u; qv[3][1] = c.f;
  }
  float m = -INFINITY, s = 0.f;
  f32x2 a[4] = {};

  uint4 w0, w1, w2, w3;
  if (e0 + 0 < e1) w0 = loadkv(kv, ssrc, e0 + 0, lane);
  if (e0 + 1 < e1) w1 = loadkv(kv, ssrc, e0 + 1, lane);
  if (e0 + 2 < e1) w2 = loadkv(kv, ssrc, e0 + 2, lane);
  if (e0 + 3 < e1) w3 = loadkv(kv, ssrc, e0 + 3, lane);
  int e = e0;
  while (e < e1) {
    {
      float sc = qdot8(qv, w0.x, w0.y) * scale;
      unsigned vz = w0.z, vw = w0.w;
      if (e + 4 < e1) w0 = loadkv(kv, ssrc, e + 4, lane);
      accum8(a, m, s, sc, vz, vw);
    }
    if (e + 1 < e1) {
      float sc = qdot8(qv, w1.x, w1.y) * scale;
      unsigned vz = w1.z, vw = w1.w;
      if (e + 5 < e1) w1 = loadkv(kv, ssrc, e + 5, lane);
      accum8(a, m, s, sc, vz, vw);
    }
    if (e + 2 < e1) {
      float sc = qdot8(qv, w2.x, w2.y) * scale;
      unsigned vz = w2.z, vw = w2.w;
      if (e + 6 < e1) w2 = loadkv(kv, ssrc, e + 6, lane);
      accum8(a, m, s, sc, vz, vw);
    }
    if (e + 3 < e1) {
      float sc = qdot8(qv, w3.x, w3.y) * scale;
      unsigned vz = w3.z, vw = w3.w;
      if (e + 7 < e1) w3 = loadkv(kv, ssrc, e + 7, lane);
      accum8(a, m, s, sc, vz, vw);
    }
    e += 4;
  }

  // normalize per head, then head-mean via cross-group shuffles
  float inv = 0.25f / (s + 1e-16f);
  float am[8];
#pragma unroll
  for (int d = 0; d < 8; ++d) {
    float ad = a[d >> 1][d & 1] * inv;
    ad += __shfl_xor(ad, 16);
    ad += __shfl_xor(ad, 32);
    am[d] = ad;  // mean over heads, replicated in all groups
  }

  // skip+residual (pre-summed in hs) + LayerNorm
  const float4* hp = reinterpret_cast<const float4*>(hs + (size_t)node * DD + l16 * 8);
  float4 h0 = hp[0], h1 = hp[1];
  float val[8];
  val[0] = am[0] + h0.x; val[1] = am[1] + h0.y; val[2] = am[2] + h0.z; val[3] = am[3] + h0.w;
  val[4] = am[4] + h1.x; val[5] = am[5] + h1.y; val[6] = am[6] + h1.z; val[7] = am[7] + h1.w;
  float sum = 0.f, sq = 0.f;
#pragma unroll
  for (int d = 0; d < 8; ++d) { sum += val[d]; sq += val[d] * val[d]; }
  sum += __shfl_xor(sum, 1); sq += __shfl_xor(sq, 1);
  sum += __shfl_xor(sum, 2); sq += __shfl_xor(sq, 2);
  sum += __shfl_xor(sum, 4); sq += __shfl_xor(sq, 4);
  sum += __shfl_xor(sum, 8); sq += __shfl_xor(sq, 8);
  float mu = sum * (1.f / 128.f);
  float var = sq * (1.f / 128.f) - mu * mu;
  float rstd = rsqrtf(var + 1e-5f);

  const float4* gp = reinterpret_cast<const float4*>(ln_g + l16 * 8);
  const float4* bp = reinterpret_cast<const float4*>(ln_b + l16 * 8);
  float4 g0 = gp[0], g1 = gp[1];
  float4 b0 = bp[0], b1 = bp[1];
  float y[8];
  y[0] = (val[0] - mu) * rstd * g0.x + b0.x;
  y[1] = (val[1] - mu) * rstd * g0.y + b0.y;
  y[2] = (val[2] - mu) * rstd * g0.z + b0.z;
  y[3] = (val[3] - mu) * rstd * g0.w + b0.w;
  y[4] = (val[4] - mu) * rstd * g1.x + b1.x;
  y[5] = (val[5] - mu) * rstd * g1.y + b1.y;
  y[6] = (val[6] - mu) * rstd * g1.z + b1.z;
  y[7] = (val[7] - mu) * rstd * g1.w + b1.w;
  if (relu_flag) {
#pragma unroll
    for (int d = 0; d < 8; ++d) y[d] = fmaxf(y[d], 0.f);
  }

  if (out_cls) {
    // fused classifier: group g computes classes g and g+4 (g<3)
    const int c0 = grp, c1 = grp + 4;
    float p0 = 0.f, p1 = 0.f;
#pragma unroll
    for (int d = 0; d < 8; ++d) {
      const float* wrow = Wc + (size_t)(l16 * 8 + d) * NCLS;
      p0 = fmaf(y[d], wrow[c0], p0);
      if (c1 < NCLS) p1 = fmaf(y[d], wrow[c1], p1);
    }
    p0 += __shfl_xor(p0, 1); p1 += __shfl_xor(p1, 1);
    p0 += __shfl_xor(p0, 2); p1 += __shfl_xor(p1, 2);
    p0 += __shfl_xor(p0, 4); p1 += __shfl_xor(p1, 4);
    p0 += __shfl_xor(p0, 8); p1 += __shfl_xor(p1, 8);
    if (l16 == 0) {
      out_cls[(size_t)node * NCLS + c0] = p0 + bc[c0];
      if (c1 < NCLS) out_cls[(size_t)node * NCLS + c1] = p1 + bc[c1];
    }
    return;  // h/hb not needed after the last layer
  }

  if (grp == 0) {
    float4* op = reinterpret_cast<float4*>(h_out + (size_t)node * DD + l16 * 8);
    op[0] = make_float4(y[0], y[1], y[2], y[3]);
    op[1] = make_float4(y[4], y[5], y[6], y[7]);
  } else if (grp == 1) {
    uint4 w;
    w.x = (unsigned)f2bf(y[0]) | ((unsigned)f2bf(y[1]) << 16);
    w.y = (unsigned)f2bf(y[2]) | ((unsigned)f2bf(y[3]) << 16);
    w.z = (unsigned)f2bf(y[4]) | ((unsigned)f2bf(y[5]) << 16);
    w.w = (unsigned)f2bf(y[6]) | ((unsigned)f2bf(y[7]) << 16);
    *reinterpret_cast<uint4*>(hb_out + (size_t)node * DD + l16 * 8) = w;
  }
}

extern "C" void kernel_launch(void* const* d_in, const int* in_sizes, int n_in,
                              void* d_out, int out_size, void* d_ws, size_t ws_size,
                              hipStream_t stream) {
  const float* x    = (const float*)d_in[0];
  const int*   ei   = (const int*)d_in[1];
  const float* W_in = (const float*)d_in[2];
  const float* b_in = (const float*)d_in[3];
  const float* Wq   = (const float*)d_in[4];
  const float* bq   = (const float*)d_in[5];
  const float* Wk   = (const float*)d_in[6];
  const float* bk   = (const float*)d_in[7];
  const float* Wv   = (const float*)d_in[8];
  const float* bv   = (const float*)d_in[9];
  const float* Wsk  = (const float*)d_in[10];
  const float* bsk  = (const float*)d_in[11];
  const float* ln_g = (const float*)d_in[12];
  const float* ln_b = (const float*)d_in[13];
  const float* Wc   = (const float*)d_in[14];
  const float* bc   = (const float*)d_in[15];
  float* out = (float*)d_out;

  char* ws = (char*)d_ws;
  size_t off = 0;
  float*  hA    = (float*)(ws + off);  off += (size_t)NN * DD * 4;
  float*  hB    = (float*)(ws + off);  off += (size_t)NN * DD * 4;
  __bf16* qb    = (__bf16*)(ws + off); off += (size_t)NN * 512 * 2;
  unsigned char* kvb = (unsigned char*)(ws + off); off += (size_t)NN * 1024;
  float*  hsb   = (float*)(ws + off);  off += (size_t)NN * DD * 4;
  __bf16* hb0   = (__bf16*)(ws + off); off += (size_t)NN * DD * 2;
  __bf16* hb1   = (__bf16*)(ws + off); off += (size_t)NN * DD * 2;
  __bf16* WT    = (__bf16*)(ws + off); off += (size_t)458752 * 2;
  float*  bcomb = (float*)(ws + off);  off += (size_t)3328 * 4;
  int* deg      = (int*)(ws + off);    off += (size_t)NN * 4;
  int* cnt      = (int*)(ws + off);    off += (size_t)NN * 4;
  int* fillp    = (int*)(ws + off);    off += (size_t)NN * 4;
  int* row_ptr  = (int*)(ws + off);    off += (size_t)(NN + 1) * 4;
  int* ssrc     = (int*)(ws + off);    off += (size_t)EE * 4;

  __bf16* W_inT = WT;
  __bf16* W2T   = WT + 32768;

  zero_ints<<<(2 * NN + 255) / 256, 256, 0, stream>>>(deg, 2 * NN);
  count_kernel<<<(EE + 255) / 256, 256, 0, stream>>>(ei, deg, cnt);
  scan_kernel<<<1, 1024, 0, stream>>>(cnt, row_ptr, fillp);
  scatter_kernel<<<(EE + 255) / 256, 256, 0, stream>>>(ei, fillp, ssrc);

  pack_weights<<<(458752 + 255) / 256, 256, 0, stream>>>(W_in, Wq, Wk, Wv, Wsk, WT);
  pack_bias<<<(3328 + 255) / 256, 256, 0, stream>>>(bq, bk, bv, bsk, bcomb);

  // h0 = x @ W_in + b_in + PE  -> hA (fp32) + hb0 (bf16)
  mfma_gemm_in<<<dim3((NN + 63) / 64, 1), 256, 0, stream>>>(x, W_inT, b_in, hA, hb0, deg);

  const float*  h_in_l[2]   = {hA, hB};
  float*        h_out_l[2]  = {hB, hA};
  const __bf16* hb_in_l[2]  = {hb0, hb1};
  __bf16*       hb_out_l[2] = {hb1, hb0};

  for (int l = 0; l < 2; ++l) {
    // XCD-swizzled flat grid: 8 xcds x 20 row-blocks x 13 col-blocks = 2080
    mfma_gemm_qkv<<<2080, 512, 0, stream>>>(hb_in_l[l], W2T + (size_t)l * 212992,
                                            bcomb + (size_t)l * 1664, h_in_l[l],
                                            qb, kvb, hsb);
    attn_fused<<<NN / 4, 256, 0, stream>>>(qb, kvb, hsb, row_ptr, ssrc,
                                           ln_g + (size_t)l * DD, ln_b + (size_t)l * DD,
                                           h_out_l[l], hb_out_l[l], (l == 0) ? 1 : 0,
                                           Wc, bc, (l == 1) ? out : nullptr);
  }
}

// Round 14
// 272.972 us; speedup vs baseline: 1.3542x; 1.0998x over previous
//
#include <hip/hip_runtime.h>
#include <math.h>

#define NN 20000
#define EE 320000
#define DIN 256
#define DD 128
#define HHEADS 4
#define NCLS 7

typedef __attribute__((ext_vector_type(8))) __bf16 bf16x8;
typedef __attribute__((ext_vector_type(4))) float f32x4;
typedef __attribute__((ext_vector_type(2))) float f32x2;

__device__ __forceinline__ unsigned short f2bf(float f) {
  union { float f; unsigned int u; } c; c.f = f;
  unsigned int r = c.u + 0x7fffu + ((c.u >> 16) & 1u);  // RNE
  return (unsigned short)(r >> 16);
}
__device__ __forceinline__ __bf16 f2bf16(float f) {
  union { unsigned short u; __bf16 b; } cv; cv.u = f2bf(f); return cv.b;
}
// fp8 e4m3 (OCP on gfx950) encode/decode via HW converts
__device__ __forceinline__ unsigned char fp8enc(float v) {
  return (unsigned char)(__builtin_amdgcn_cvt_pk_fp8_f32(v, 0.f, 0, false) & 0xff);
}

// ---------------- utility ----------------
__global__ void zero_ints(int* __restrict__ p, int n) {
  int i = blockIdx.x * blockDim.x + threadIdx.x;
  if (i < n) p[i] = 0;
}

// ---------------- CSR build ----------------
__global__ void count_kernel(const int* __restrict__ ei, int* __restrict__ deg_src,
                             int* __restrict__ cnt_dst) {
  int e = blockIdx.x * blockDim.x + threadIdx.x;
  if (e >= EE) return;
  atomicAdd(&deg_src[ei[e]], 1);
  atomicAdd(&cnt_dst[ei[EE + e]], 1);
}

// ---- 3-phase multi-block exclusive scan of cnt[NN] -> row_ptr, fillp ----
// phase 1: per-block local exclusive scan + block sum
__global__ __launch_bounds__(1024) void scan_local(const int* __restrict__ cnt,
                                                   int* __restrict__ row_ptr,
                                                   int* __restrict__ bsum) {
  __shared__ int wsum[16];
  const int tid = threadIdx.x;
  const int wid = tid >> 6, lane = tid & 63;
  const int i = blockIdx.x * 1024 + tid;
  int x = (i < NN) ? cnt[i] : 0;
  int v = x;
#pragma unroll
  for (int off = 1; off < 64; off <<= 1) {
    int t = __shfl_up(v, off);
    if (lane >= off) v += t;
  }
  if (lane == 63) wsum[wid] = v;
  __syncthreads();
  int woff = 0;
  for (int w = 0; w < wid; ++w) woff += wsum[w];
  if (i < NN) row_ptr[i] = woff + v - x;  // local exclusive
  if (tid == 1023) {
    int tot = 0;
    for (int w = 0; w < 16; ++w) tot += wsum[w];
    bsum[blockIdx.x] = tot;
  }
}
// phase 2: one wave scans the 20 block sums -> exclusive boff; writes row_ptr[NN]
__global__ void scan_boff(const int* __restrict__ bsum, int* __restrict__ boff,
                          int* __restrict__ row_ptr) {
  const int t = threadIdx.x;  // 64 threads
  int x = (t < 20) ? bsum[t] : 0;
  int v = x;
#pragma unroll
  for (int off = 1; off < 64; off <<= 1) {
    int tt = __shfl_up(v, off);
    if (t >= off) v += tt;
  }
  if (t < 20) boff[t] = v - x;
  if (t == 0) row_ptr[NN] = EE;
}
// phase 3: add block offsets; also fill fillp
__global__ __launch_bounds__(1024) void scan_add(int* __restrict__ row_ptr,
                                                 const int* __restrict__ boff,
                                                 int* __restrict__ fillp) {
  const int i = blockIdx.x * 1024 + threadIdx.x;
  if (i >= NN) return;
  int v = row_ptr[i] + boff[blockIdx.x];
  row_ptr[i] = v;
  fillp[i] = v;
}

__global__ void scatter_kernel(const int* __restrict__ ei, int* __restrict__ fillp,
                               int* __restrict__ ssrc) {
  int e = blockIdx.x * blockDim.x + threadIdx.x;
  if (e >= EE) return;
  int s = ei[e], d = ei[EE + e];
  int pos = atomicAdd(&fillp[d], 1);
  ssrc[pos] = s;
}

// ---------------- pack weights ----------------
// WT (bf16): W_inT[128][256] @0 | W2T[2][1664][128] @32768 | WcT[16][128] @458752
// W2T column order: [q 0-511][kv-blocked 512-1535][skip 1536-1663]
// kv region col rr (0-based): b=rr>>7, cc=rr&127, is_v=(cc>=64), dim=b*64+(cc&63)
//   -> output byte b*128 + ((cc&63)>>3)*16 + is_v*8 + (cc&7)  (contiguous 128B per block)
__global__ void pack_weights(const float* __restrict__ W_in, const float* __restrict__ Wq,
                             const float* __restrict__ Wk, const float* __restrict__ Wv,
                             const float* __restrict__ Wsk, const float* __restrict__ Wc,
                             __bf16* __restrict__ WT) {
  int idx = blockIdx.x * blockDim.x + threadIdx.x;
  if (idx >= 460800) return;
  float val;
  if (idx < 32768) {                       // W_inT: [m][k], m<128, k<256
    int m = idx >> 8, k = idx & 255;
    val = W_in[k * 128 + m];
  } else if (idx < 458752) {               // W2T: [l][r][kk]
    int t = idx - 32768;
    int l = t / 212992; int t2 = t - l * 212992;
    int r = t2 >> 7, kk = t2 & 127;
    if (r < 512) {
      val = Wq[l * 65536 + kk * 512 + r];
    } else if (r < 1536) {
      int rr = r - 512;
      int b = rr >> 7, cc = rr & 127;
      int dim = b * 64 + (cc & 63);
      val = (cc >= 64) ? Wv[l * 65536 + kk * 512 + dim]
                       : Wk[l * 65536 + kk * 512 + dim];
    } else {
      val = Wsk[l * 16384 + kk * 128 + (r - 1536)];
    }
  } else {                                 // WcT: [r][kk], r<16 (pad), kk<128
    int t = idx - 458752;
    int r = t >> 7, kk = t & 127;
    val = (r < NCLS) ? Wc[kk * NCLS + r] : 0.f;
  }
  WT[idx] = f2bf16(val);
}

// bcomb[2][1664] | bcpad[16]  (same kv column remap)
__global__ void pack_bias(const float* __restrict__ bq, const float* __restrict__ bk,
                          const float* __restrict__ bv, const float* __restrict__ bsk,
                          const float* __restrict__ bc, float* __restrict__ bcomb,
                          float* __restrict__ bcpad) {
  int idx = blockIdx.x * blockDim.x + threadIdx.x;
  if (idx < 3328) {
    int l = idx / 1664, r = idx % 1664;
    float v;
    if (r < 512) {
      v = bq[l * 512 + r];
    } else if (r < 1536) {
      int rr = r - 512;
      int b = rr >> 7, cc = rr & 127;
      int dim = b * 64 + (cc & 63);
      v = (cc >= 64) ? bv[l * 512 + dim] : bk[l * 512 + dim];
    } else {
      v = bsk[l * 128 + (r - 1536)];
    }
    bcomb[idx] = v;
  } else if (idx < 3344) {
    int r = idx - 3328;
    bcpad[r] = (r < NCLS) ? bc[r] : 0.f;
  }
}

// ---------------- input GEMM (K=256, fp32 A, cvt in staging): BM=64, BN=128 ----------------
__global__ __launch_bounds__(256) void mfma_gemm_in(
    const float* __restrict__ A, const __bf16* __restrict__ BT,
    const float* __restrict__ bias, float* __restrict__ o_f32,
    __bf16* __restrict__ o_bf0, const int* __restrict__ deg) {
  constexpr int K = 256;
  __shared__ __attribute__((aligned(16))) __bf16 As[64][136];
  __shared__ __attribute__((aligned(16))) __bf16 Bs[128][136];
  const int tid = threadIdx.x;
  const int brow = blockIdx.x * 64;
  const int wave = tid >> 6, lane = tid & 63;
  const int wm = wave & 1, wn = wave >> 1;
  const int lm = lane & 15, lk = (lane >> 4) * 8;
  const int srow16 = tid >> 4;
  const int sc8 = (tid & 15) * 8;
  f32x4 acc[2][4] = {};
  for (int k0 = 0; k0 < K; k0 += 128) {
    if (k0) __syncthreads();
#pragma unroll
    for (int t = 0; t < 4; ++t) {
      int row = t * 16 + srow16;
      int arow = brow + row;
      arow = (arow < NN) ? arow : (NN - 1);
      const float* ap = A + (size_t)arow * K + k0 + sc8;
      float4 a0 = *(const float4*)ap, a1 = *(const float4*)(ap + 4);
      uint4 w;
      w.x = (unsigned)f2bf(a0.x) | ((unsigned)f2bf(a0.y) << 16);
      w.y = (unsigned)f2bf(a0.z) | ((unsigned)f2bf(a0.w) << 16);
      w.z = (unsigned)f2bf(a1.x) | ((unsigned)f2bf(a1.y) << 16);
      w.w = (unsigned)f2bf(a1.z) | ((unsigned)f2bf(a1.w) << 16);
      *reinterpret_cast<uint4*>(&As[row][sc8]) = w;
    }
#pragma unroll
    for (int t = 0; t < 8; ++t) {
      int row = t * 16 + srow16;
      *reinterpret_cast<uint4*>(&Bs[row][sc8]) =
          *reinterpret_cast<const uint4*>(BT + (size_t)row * K + k0 + sc8);
    }
    __syncthreads();
#pragma unroll
    for (int ks = 0; ks < 4; ++ks) {
      bf16x8 af[2], bfr[4];
#pragma unroll
      for (int i = 0; i < 2; ++i)
        af[i] = *reinterpret_cast<const bf16x8*>(&As[wm * 32 + i * 16 + lm][ks * 32 + lk]);
#pragma unroll
      for (int j = 0; j < 4; ++j)
        bfr[j] = *reinterpret_cast<const bf16x8*>(&Bs[wn * 64 + j * 16 + lm][ks * 32 + lk]);
#pragma unroll
      for (int i = 0; i < 2; ++i)
#pragma unroll
        for (int j = 0; j < 4; ++j)
          acc[i][j] = __builtin_amdgcn_mfma_f32_16x16x32_bf16(af[i], bfr[j], acc[i][j], 0, 0, 0);
    }
  }
#pragma unroll
  for (int i = 0; i < 2; ++i) {
#pragma unroll
    for (int j = 0; j < 4; ++j) {
      const int col = wn * 64 + j * 16 + lm;
      const float bb = bias[col];
#pragma unroll
      for (int r = 0; r < 4; ++r) {
        const int row = brow + wm * 32 + i * 16 + (lane >> 4) * 4 + r;
        if (row >= NN) continue;
        float val = acc[i][j][r] + bb;
        float dg = (float)deg[row];
        float freq = dg * __expf(-0.07195578415606394f * (float)col);  // 10000^(-col/128)
        val += (col & 1) ? __cosf(freq) : __sinf(freq);
        o_f32[(size_t)row * DD + col] = val;
        o_bf0[(size_t)row * DD + col] = f2bf16(val);
      }
    }
  }
}

// ---------------- QKV GEMM: 8 waves, BM=128 x BN=128, B-in-LDS, A direct ----------------
// XCD-swizzled flat grid (2080 blocks): xcd gets a 20-rowblock stripe x all 13 col-blocks
// Epilogue: q and kv staged through LDS -> fully coalesced wide stores (no partial lines)
__global__ __launch_bounds__(512) void mfma_gemm_qkv(
    const __bf16* __restrict__ A, const __bf16* __restrict__ BT,
    const float* __restrict__ bias, const float* __restrict__ resid,
    __bf16* __restrict__ o_q, unsigned char* __restrict__ o_fp8,
    float* __restrict__ o_hs) {
  __shared__ __attribute__((aligned(16))) unsigned char smem[34816];
  auto Bs = reinterpret_cast<__bf16(*)[136]>(smem);

  const int bid = blockIdx.x;
  const int xcd = bid & 7;
  const int jj = bid >> 3;            // 0..259
  const int brow128 = xcd * 20 + (jj % 20);
  if (brow128 * 128 >= NN) return;
  const int brow = brow128 * 128;
  const int bcol = (jj / 20) * 128;   // 0..12 * 128

  const int tid = threadIdx.x;
  const int wave = tid >> 6, lane = tid & 63;
  const int wm = wave & 3, wn = wave >> 2;
  const int lm = lane & 15, lk = (lane >> 4) * 8, l4 = (lane >> 4) * 4;
  const int srow32 = tid >> 4;        // 0..31
  const int sc8 = (tid & 15) * 8;     // 0..120

  // B slice loads FIRST (pre-ds_write waitcnt drains only these 4)
  uint4 breg[4];
#pragma unroll
  for (int t = 0; t < 4; ++t)
    breg[t] = *reinterpret_cast<const uint4*>(BT + (size_t)(bcol + t * 32 + srow32) * 128 + sc8);

  // A fragments direct to registers (stay in flight across the barrier)
  bf16x8 af[2][4];
#pragma unroll
  for (int i = 0; i < 2; ++i) {
    int row = brow + wm * 32 + i * 16 + lm;
    row = (row < NN) ? row : (NN - 1);
    const __bf16* ap = A + (size_t)row * 128 + lk;
#pragma unroll
    for (int ks = 0; ks < 4; ++ks)
      af[i][ks] = *reinterpret_cast<const bf16x8*>(ap + ks * 32);
  }

#pragma unroll
  for (int t = 0; t < 4; ++t)
    *reinterpret_cast<uint4*>(&Bs[t * 32 + srow32][sc8]) = breg[t];
  __syncthreads();

  f32x4 acc[2][4] = {};
#pragma unroll
  for (int ks = 0; ks < 4; ++ks) {
    bf16x8 bfr[4];
#pragma unroll
    for (int j = 0; j < 4; ++j)
      bfr[j] = *reinterpret_cast<const bf16x8*>(&Bs[wn * 64 + j * 16 + lm][ks * 32 + lk]);
#pragma unroll
    for (int i = 0; i < 2; ++i)
#pragma unroll
      for (int j = 0; j < 4; ++j)
        acc[i][j] = __builtin_amdgcn_mfma_f32_16x16x32_bf16(af[i][ks], bfr[j], acc[i][j], 0, 0, 0);
  }

  __syncthreads();  // all Bs reads done; smem is reusable for epilogue staging

  if (bcol < 512) {
    // ---- q: stage bf16 tile [128][136], then 256B-per-row coalesced stores ----
    auto qt = reinterpret_cast<__bf16(*)[136]>(smem);
#pragma unroll
    for (int i = 0; i < 2; ++i)
#pragma unroll
      for (int j = 0; j < 4; ++j) {
        const int cc = wn * 64 + j * 16 + lm;
        const float bb = bias[bcol + cc];
#pragma unroll
        for (int r = 0; r < 4; ++r)
          qt[wm * 32 + i * 16 + l4 + r][cc] = f2bf16(acc[i][j][r] + bb);
      }
    __syncthreads();
#pragma unroll
    for (int p = 0; p < 4; ++p) {
      int slot = tid + p * 512;
      int row = slot >> 4, c = slot & 15;
      int grow = brow + row;
      if (grow < NN)
        *reinterpret_cast<uint4*>(o_q + (size_t)grow * 512 + bcol + c * 8) =
            *reinterpret_cast<const uint4*>(&qt[row][c * 8]);
    }
  } else if (bcol < 1536) {
    // ---- kv: stage fp8 byte tile [128][128] (XOR-swizzled), then 128B-per-row stores ----
    auto kt = reinterpret_cast<unsigned char(*)[128]>(smem);
    const int b = (bcol - 512) >> 7;
#pragma unroll
    for (int i = 0; i < 2; ++i)
#pragma unroll
      for (int j = 0; j < 4; ++j) {
        const float bb = bias[bcol + wn * 64 + j * 16 + lm];
        const int boff = (j * 2 + (lm >> 3)) * 16 + wn * 8 + (lm & 7);
#pragma unroll
        for (int r = 0; r < 4; ++r) {
          int lrow = wm * 32 + i * 16 + l4 + r;
          kt[lrow][boff ^ (((lrow >> 2) & 3) << 5)] = fp8enc(acc[i][j][r] + bb);
        }
      }
    __syncthreads();
#pragma unroll
    for (int p = 0; p < 2; ++p) {
      int slot = tid + p * 512;
      int row = slot >> 3, c = slot & 7;
      int grow = brow + row;
      if (grow < NN)
        *reinterpret_cast<uint4*>(o_fp8 + (size_t)grow * 1024 + b * 128 + c * 16) =
            *reinterpret_cast<const uint4*>(&kt[row][(c * 16) ^ (((row >> 2) & 3) << 5)]);
    }
  } else {
    // ---- hs: direct fp32 (full-line runs) + residual pre-sum ----
#pragma unroll
    for (int i = 0; i < 2; ++i)
#pragma unroll
      for (int j = 0; j < 4; ++j) {
        const int col = bcol + wn * 64 + j * 16 + lm;
        const float bb = bias[col];
#pragma unroll
        for (int r = 0; r < 4; ++r) {
          const int row = brow + wm * 32 + i * 16 + l4 + r;
          if (row >= NN) continue;
          o_hs[(size_t)row * DD + (col - 1536)] =
              acc[i][j][r] + bb + resid[(size_t)row * DD + (col - 1536)];
        }
      }
  }
}

// ---------------- classifier: out[N][7] = hb @ WcT + bc; 16-col B tile ----------------
__global__ __launch_bounds__(256) void mfma_gemm_cls(
    const __bf16* __restrict__ A, const __bf16* __restrict__ BT,
    const float* __restrict__ bias, float* __restrict__ out) {
  __shared__ __attribute__((aligned(16))) __bf16 Bs[16][136];
  const int tid = threadIdx.x;
  const int wave = tid >> 6, lane = tid & 63;
  const int lm = lane & 15, lk = (lane >> 4) * 8, l4 = (lane >> 4) * 4;
  const int brow = blockIdx.x * 128 + wave * 32;
  {  // stage 16 rows x 128 k
    int srow = tid >> 4, sc8 = (tid & 15) * 8;
    *reinterpret_cast<uint4*>(&Bs[srow][sc8]) =
        *reinterpret_cast<const uint4*>(BT + (size_t)srow * 128 + sc8);
  }
  __syncthreads();
  bf16x8 af[2][4];
#pragma unroll
  for (int i = 0; i < 2; ++i) {
    int row = brow + i * 16 + lm;
    row = (row < NN) ? row : (NN - 1);
    const __bf16* ap = A + (size_t)row * 128 + lk;
#pragma unroll
    for (int ks = 0; ks < 4; ++ks) af[i][ks] = *reinterpret_cast<const bf16x8*>(ap + ks * 32);
  }
  f32x4 acc[2] = {};
#pragma unroll
  for (int ks = 0; ks < 4; ++ks) {
    bf16x8 bfr = *reinterpret_cast<const bf16x8*>(&Bs[lm][ks * 32 + lk]);
#pragma unroll
    for (int i = 0; i < 2; ++i)
      acc[i] = __builtin_amdgcn_mfma_f32_16x16x32_bf16(af[i][ks], bfr, acc[i], 0, 0, 0);
  }
  if (lm < NCLS) {
    const float bb = bias[lm];
#pragma unroll
    for (int i = 0; i < 2; ++i) {
#pragma unroll
      for (int r = 0; r < 4; ++r) {
        int row = brow + i * 16 + l4 + r;
        if (row < NN) out[(size_t)row * NCLS + lm] = acc[i][r] + bb;
      }
    }
  }
}

// ---------------- attention helpers (packed f32) ----------------
__device__ __forceinline__ uint4 loadkv(const unsigned char* __restrict__ kv,
                                        const int* __restrict__ ssrc, int ee, int lane) {
  return *reinterpret_cast<const uint4*>(kv + (size_t)ssrc[ee] * 1024 + lane * 16);
}
__device__ __forceinline__ float qdot8(const f32x2 (&qv)[4], unsigned kx, unsigned ky) {
  f32x2 kd0 = __builtin_amdgcn_cvt_pk_f32_fp8((int)kx, false);
  f32x2 kd1 = __builtin_amdgcn_cvt_pk_f32_fp8((int)kx, true);
  f32x2 kd2 = __builtin_amdgcn_cvt_pk_f32_fp8((int)ky, false);
  f32x2 kd3 = __builtin_amdgcn_cvt_pk_f32_fp8((int)ky, true);
  f32x2 d2 = qv[0] * kd0;
  d2 = qv[1] * kd1 + d2;
  d2 = qv[2] * kd2 + d2;
  d2 = qv[3] * kd3 + d2;
  float d = d2[0] + d2[1];
  d += __shfl_xor(d, 1);
  d += __shfl_xor(d, 2);
  d += __shfl_xor(d, 4);
  d += __shfl_xor(d, 8);
  return d;
}
__device__ __forceinline__ void accum8(f32x2 (&a)[4], float& m, float& s, float sc,
                                       unsigned vz, unsigned vw) {
  if (sc > m) {  // rare after warm-up
    float c = __expf(m - sc);
    f32x2 c2 = {c, c};
    s *= c;
#pragma unroll
    for (int d = 0; d < 4; ++d) a[d] *= c2;
    m = sc;
  }
  float w = __expf(sc - m);
  s += w;
  f32x2 w2 = {w, w};
  f32x2 vd0 = __builtin_amdgcn_cvt_pk_f32_fp8((int)vz, false);
  f32x2 vd1 = __builtin_amdgcn_cvt_pk_f32_fp8((int)vz, true);
  f32x2 vd2 = __builtin_amdgcn_cvt_pk_f32_fp8((int)vw, false);
  f32x2 vd3 = __builtin_amdgcn_cvt_pk_f32_fp8((int)vw, true);
  a[0] = w2 * vd0 + a[0];
  a[1] = w2 * vd1 + a[1];
  a[2] = w2 * vd2 + a[2];
  a[3] = w2 * vd3 + a[3];
}

// ---------------- fused attention + head-mean + skip/resid + LN (+ReLU) ----------------
__global__ __launch_bounds__(256) void attn_fused(
    const __bf16* __restrict__ qb, const unsigned char* __restrict__ kv,
    const float* __restrict__ hs,
    const int* __restrict__ row_ptr, const int* __restrict__ ssrc,
    const float* __restrict__ ln_g, const float* __restrict__ ln_b,
    float* __restrict__ h_out, __bf16* __restrict__ hb_out, int relu_flag) {
  const int node = blockIdx.x * 4 + (threadIdx.x >> 6);
  const int lane = threadIdx.x & 63;
  const int grp = lane >> 4, l16 = lane & 15;
  const int e0 = row_ptr[node], e1 = row_ptr[node + 1];
  const float scale = 0.088388347648318447f;  // 1/sqrt(128)

  f32x2 qv[4];
  {
    uint4 qw = *reinterpret_cast<const uint4*>(qb + (size_t)node * 512 + lane * 8);
    union { unsigned u; float f; } c;
    c.u = qw.x << 16; qv[0][0] = c.f; c.u = qw.x & 0xffff0000u; qv[0][1] = c.f;
    c.u = qw.y << 16; qv[1][0] = c.f; c.u = qw.y & 0xffff0000u; qv[1][1] = c.f;
    c.u = qw.z << 16; qv[2][0] = c.f; c.u = qw.z & 0xffff0000u; qv[2][1] = c.f;
    c.u = qw.w << 16; qv[3][0] = c.f; c.u = qw.w & 0xffff0000u; qv[3][1] = c.f;
  }
  float m = -INFINITY, s = 0.f;
  f32x2 a[4] = {};

  uint4 w0, w1, w2, w3;
  if (e0 + 0 < e1) w0 = loadkv(kv, ssrc, e0 + 0, lane);
  if (e0 + 1 < e1) w1 = loadkv(kv, ssrc, e0 + 1, lane);
  if (e0 + 2 < e1) w2 = loadkv(kv, ssrc, e0 + 2, lane);
  if (e0 + 3 < e1) w3 = loadkv(kv, ssrc, e0 + 3, lane);
  int e = e0;
  while (e < e1) {
    {
      float sc = qdot8(qv, w0.x, w0.y) * scale;
      unsigned vz = w0.z, vw = w0.w;
      if (e + 4 < e1) w0 = loadkv(kv, ssrc, e + 4, lane);
      accum8(a, m, s, sc, vz, vw);
    }
    if (e + 1 < e1) {
      float sc = qdot8(qv, w1.x, w1.y) * scale;
      unsigned vz = w1.z, vw = w1.w;
      if (e + 5 < e1) w1 = loadkv(kv, ssrc, e + 5, lane);
      accum8(a, m, s, sc, vz, vw);
    }
    if (e + 2 < e1) {
      float sc = qdot8(qv, w2.x, w2.y) * scale;
      unsigned vz = w2.z, vw = w2.w;
      if (e + 6 < e1) w2 = loadkv(kv, ssrc, e + 6, lane);
      accum8(a, m, s, sc, vz, vw);
    }
    if (e + 3 < e1) {
      float sc = qdot8(qv, w3.x, w3.y) * scale;
      unsigned vz = w3.z, vw = w3.w;
      if (e + 7 < e1) w3 = loadkv(kv, ssrc, e + 7, lane);
      accum8(a, m, s, sc, vz, vw);
    }
    e += 4;
  }

  // normalize per head, then head-mean via cross-group shuffles
  float inv = 0.25f / (s + 1e-16f);
  float am[8];
#pragma unroll
  for (int d = 0; d < 8; ++d) {
    float ad = a[d >> 1][d & 1] * inv;
    ad += __shfl_xor(ad, 16);
    ad += __shfl_xor(ad, 32);
    am[d] = ad;  // mean over heads, replicated in all groups
  }

  // skip+residual (pre-summed in hs) + LayerNorm
  const float4* hp = reinterpret_cast<const float4*>(hs + (size_t)node * DD + l16 * 8);
  float4 h0 = hp[0], h1 = hp[1];
  float val[8];
  val[0] = am[0] + h0.x; val[1] = am[1] + h0.y; val[2] = am[2] + h0.z; val[3] = am[3] + h0.w;
  val[4] = am[4] + h1.x; val[5] = am[5] + h1.y; val[6] = am[6] + h1.z; val[7] = am[7] + h1.w;
  float sum = 0.f, sq = 0.f;
#pragma unroll
  for (int d = 0; d < 8; ++d) { sum += val[d]; sq += val[d] * val[d]; }
  sum += __shfl_xor(sum, 1); sq += __shfl_xor(sq, 1);
  sum += __shfl_xor(sum, 2); sq += __shfl_xor(sq, 2);
  sum += __shfl_xor(sum, 4); sq += __shfl_xor(sq, 4);
  sum += __shfl_xor(sum, 8); sq += __shfl_xor(sq, 8);
  float mu = sum * (1.f / 128.f);
  float var = sq * (1.f / 128.f) - mu * mu;
  float rstd = rsqrtf(var + 1e-5f);

  const float4* gp = reinterpret_cast<const float4*>(ln_g + l16 * 8);
  const float4* bp = reinterpret_cast<const float4*>(ln_b + l16 * 8);
  float4 g0 = gp[0], g1 = gp[1];
  float4 b0 = bp[0], b1 = bp[1];
  float y[8];
  y[0] = (val[0] - mu) * rstd * g0.x + b0.x;
  y[1] = (val[1] - mu) * rstd * g0.y + b0.y;
  y[2] = (val[2] - mu) * rstd * g0.z + b0.z;
  y[3] = (val[3] - mu) * rstd * g0.w + b0.w;
  y[4] = (val[4] - mu) * rstd * g1.x + b1.x;
  y[5] = (val[5] - mu) * rstd * g1.y + b1.y;
  y[6] = (val[6] - mu) * rstd * g1.z + b1.z;
  y[7] = (val[7] - mu) * rstd * g1.w + b1.w;
  if (relu_flag) {
#pragma unroll
    for (int d = 0; d < 8; ++d) y[d] = fmaxf(y[d], 0.f);
  }
  if (grp == 0) {
    float4* op = reinterpret_cast<float4*>(h_out + (size_t)node * DD + l16 * 8);
    op[0] = make_float4(y[0], y[1], y[2], y[3]);
    op[1] = make_float4(y[4], y[5], y[6], y[7]);
  } else if (grp == 1) {
    uint4 w;
    w.x = (unsigned)f2bf(y[0]) | ((unsigned)f2bf(y[1]) << 16);
    w.y = (unsigned)f2bf(y[2]) | ((unsigned)f2bf(y[3]) << 16);
    w.z = (unsigned)f2bf(y[4]) | ((unsigned)f2bf(y[5]) << 16);
    w.w = (unsigned)f2bf(y[6]) | ((unsigned)f2bf(y[7]) << 16);
    *reinterpret_cast<uint4*>(hb_out + (size_t)node * DD + l16 * 8) = w;
  }
}

extern "C" void kernel_launch(void* const* d_in, const int* in_sizes, int n_in,
                              void* d_out, int out_size, void* d_ws, size_t ws_size,
                              hipStream_t stream) {
  const float* x    = (const float*)d_in[0];
  const int*   ei   = (const int*)d_in[1];
  const float* W_in = (const float*)d_in[2];
  const float* b_in = (const float*)d_in[3];
  const float* Wq   = (const float*)d_in[4];
  const float* bq   = (const float*)d_in[5];
  const float* Wk   = (const float*)d_in[6];
  const float* bk   = (const float*)d_in[7];
  const float* Wv   = (const float*)d_in[8];
  const float* bv   = (const float*)d_in[9];
  const float* Wsk  = (const float*)d_in[10];
  const float* bsk  = (const float*)d_in[11];
  const float* ln_g = (const float*)d_in[12];
  const float* ln_b = (const float*)d_in[13];
  const float* Wc   = (const float*)d_in[14];
  const float* bc   = (const float*)d_in[15];
  float* out = (float*)d_out;

  char* ws = (char*)d_ws;
  size_t off = 0;
  float*  hA    = (float*)(ws + off);  off += (size_t)NN * DD * 4;
  float*  hB    = (float*)(ws + off);  off += (size_t)NN * DD * 4;
  __bf16* qb    = (__bf16*)(ws + off); off += (size_t)NN * 512 * 2;
  unsigned char* kvb = (unsigned char*)(ws + off); off += (size_t)NN * 1024;
  float*  hsb   = (float*)(ws + off);  off += (size_t)NN * DD * 4;
  __bf16* hb0   = (__bf16*)(ws + off); off += (size_t)NN * DD * 2;
  __bf16* hb1   = (__bf16*)(ws + off); off += (size_t)NN * DD * 2;
  __bf16* WT    = (__bf16*)(ws + off); off += (size_t)460800 * 2;
  float*  bcomb = (float*)(ws + off);  off += (size_t)3328 * 4;
  float*  bcpad = (float*)(ws + off);  off += (size_t)16 * 4;
  int* deg      = (int*)(ws + off);    off += (size_t)NN * 4;
  int* cnt      = (int*)(ws + off);    off += (size_t)NN * 4;
  int* bsum     = (int*)(ws + off);    off += (size_t)32 * 4;
  int* boff     = (int*)(ws + off);    off += (size_t)32 * 4;
  int* fillp    = (int*)(ws + off);    off += (size_t)NN * 4;
  int* row_ptr  = (int*)(ws + off);    off += (size_t)(NN + 1) * 4;
  int* ssrc     = (int*)(ws + off);    off += (size_t)EE * 4;

  __bf16* W_inT = WT;
  __bf16* W2T   = WT + 32768;
  __bf16* WcT   = WT + 458752;

  zero_ints<<<(2 * NN + 255) / 256, 256, 0, stream>>>(deg, 2 * NN);
  count_kernel<<<(EE + 255) / 256, 256, 0, stream>>>(ei, deg, cnt);
  scan_local<<<20, 1024, 0, stream>>>(cnt, row_ptr, bsum);
  scan_boff<<<1, 64, 0, stream>>>(bsum, boff, row_ptr);
  scan_add<<<20, 1024, 0, stream>>>(row_ptr, boff, fillp);
  scatter_kernel<<<(EE + 255) / 256, 256, 0, stream>>>(ei, fillp, ssrc);

  pack_weights<<<(460800 + 255) / 256, 256, 0, stream>>>(W_in, Wq, Wk, Wv, Wsk, Wc, WT);
  pack_bias<<<(3344 + 255) / 256, 256, 0, stream>>>(bq, bk, bv, bsk, bc, bcomb, bcpad);

  // h0 = x @ W_in + b_in + PE  -> hA (fp32) + hb0 (bf16)
  mfma_gemm_in<<<dim3((NN + 63) / 64, 1), 256, 0, stream>>>(x, W_inT, b_in, hA, hb0, deg);

  const float*  h_in_l[2]   = {hA, hB};
  float*        h_out_l[2]  = {hB, hA};
  const __bf16* hb_in_l[2]  = {hb0, hb1};
  __bf16*       hb_out_l[2] = {hb1, hb0};

  for (int l = 0; l < 2; ++l) {
    // XCD-swizzled flat grid: 8 xcds x 20 row-blocks x 13 col-blocks = 2080
    mfma_gemm_qkv<<<2080, 512, 0, stream>>>(hb_in_l[l], W2T + (size_t)l * 212992,
                                            bcomb + (size_t)l * 1664, h_in_l[l],
                                            qb, kvb, hsb);
    attn_fused<<<NN / 4, 256, 0, stream>>>(qb, kvb, hsb, row_ptr, ssrc,
                                           ln_g + (size_t)l * DD, ln_b + (size_t)l * DD,
                                           h_out_l[l], hb_out_l[l], (l == 0) ? 1 : 0);
  }

  // classifier: out = h @ Wc + bc  (A = hb0, final bf16 h)
  mfma_gemm_cls<<<dim3((NN + 127) / 128, 1), 256, 0, stream>>>(hb0, WcT, bcpad, out);
}